// Round 13
// baseline (137.640 us; speedup 1.0000x reference)
//
#include <hip/hip_runtime.h>
#include <hip/hip_bf16.h>

// GCN layer: out = relu( D^-1/2 (dedup(A) + I) D^-1/2 (X @ W) )
// N=10000, E=320000, F=256.
// Storage: fp32 X/W/out (PROVEN). Edges: int32 expected, int64 tolerated
// via per-wave ballot detect.
// Cost model (r1-r12 measured):
//  - ~300k+ device-scope atomic RMWs cost 45-50us regardless of structure
//    -> ZERO global atomics anywhere (r11/r12 architecture, 137->127us).
//  - Pipeline is traffic-sensitive at ~5-6 TB/s effective: r12's region
//    24->7 MB bought exactly the predicted ~10us.
//  - acc[16] GEMM starved regalloc (r8); GEMM-v2 = LDS-staged X + acc[4].
//  - LDS atomics cheap; block-level fusion safe (r3), thread-level not (r6).
// THIS ROUND: gather is the last traffic elephant (~170 MB logical H reads:
// each 512B H row re-read by ~32 random in-neighbors; H=5.1MB > 4MiB XCD L2
// -> thrash to L3/HBM). SPLIT FEATURES: H = [2][N][128] bf16, each plane
// 2.56 MB = L2-resident per XCD. k_gather: 5000 blocks, plane = blk/2500;
// ordered dispatch gives temporal phase separation -> plane reads hit L2.
// Inner loop simplified: 4 lane-groups x 16 process 4 neighbors/iter via
// broadcast adj/deg loads (no shfl cache, no c<=64 cap), shfl_xor(16,32)
// reduction, coalesced half-row writes. GEMM store routed per col plane.
// 5 launches: k_pre(Wt) -> k_bucket_gemm -> k_fillscan -> k_deg -> k_gather.
//
// ws layout (bytes), ~20.2 MB (ws is 256 MiB):
//   deg    i32[N]           @ 0
//   cnt    i32[N]           @ 40,960
//   adj    i32[N*96]        @ 81,920
//   Wt     bf16[F*F]        @ 3,921,920
//   H      bf16[2][N][128]  @ 4,052,992   (split feature planes, 5.12 MB)
//   region i32[157*11200]   @ 9,172,992   (7.03 MB bucket blobs)
//   part32 u32[400*2500]    @ 16,206,592  (4 MB byte-lane deg partials)

constexpr int N = 10000;
constexpr int E = 320000;
constexpr int F = 256;
constexpr int DEGCAP = 96;   // Poisson(32): P(any deduped degree >= 96) ~ 1e-16
constexpr int GROWS = 25;    // rows per group (fillscan block)
constexpr int NG = N / GROWS;        // 400 groups
constexpr int EPB = 2048;    // edges per bucket block
constexpr int BCAP = 28;     // Poisson(5.12): P(>28) ~ 3e-12 x 63k pairs ~ 2e-7
constexpr int REG_PB = NG * BCAP;    // 11200 ints per source block

constexpr int BKT_BLKS  = (E + EPB - 1) / EPB;  // 157 (last block 1536 edges)
constexpr int GEMM_BLKS = (N + 31) / 32;        // 313 (last block 16 rows)

constexpr size_t OFF_DEG  = 0;
constexpr size_t OFF_CNT  = 40960;
constexpr size_t OFF_ADJ  = 81920;
constexpr size_t OFF_WT   = OFF_ADJ + 4ull * N * DEGCAP;        // 3,921,920
constexpr size_t OFF_H    = OFF_WT + 2ull * F * F;              // 4,052,992
constexpr size_t OFF_REG  = OFF_H + 2ull * N * F;               // 9,172,992
constexpr size_t OFF_PART = OFF_REG + 4ull * BKT_BLKS * REG_PB; // 16,206,592

typedef short s8v __attribute__((ext_vector_type(8)));   // 8 bf16 = 4 VGPRs
typedef float f4v __attribute__((ext_vector_type(4)));   // MFMA accumulator
typedef unsigned u4v __attribute__((ext_vector_type(4)));

__device__ __forceinline__ float bf2f(unsigned short u) {
    union { unsigned u; float f; } c; c.u = (unsigned)u << 16; return c.f;
}
__device__ __forceinline__ unsigned short f2bf(float f) {
    union { __hip_bfloat16 b; unsigned short s; } c; c.b = __float2bfloat16(f); return c.s;
}

// 64 blocks: W (fp32) -> Wt (bf16, transposed). Region needs no prefill
// (raw blob flush writes every byte); cnt/deg/part written downstream.
__global__ void k_pre(const float* __restrict__ W, unsigned short* __restrict__ Wt) {
    __shared__ unsigned short ls[4][F];
    int n0 = blockIdx.x * 4;
    int k = threadIdx.x;
    float4 v = *(const float4*)&W[k * F + n0];
    ls[0][k] = f2bf(v.x); ls[1][k] = f2bf(v.y);
    ls[2][k] = f2bf(v.z); ls[3][k] = f2bf(v.w);
    __syncthreads();
    int nn = threadIdx.x >> 6;
    int kk = (threadIdx.x & 63) * 4;
    uint2 o;
    o.x = (unsigned)ls[nn][kk]     | ((unsigned)ls[nn][kk + 1] << 16);
    o.y = (unsigned)ls[nn][kk + 2] | ((unsigned)ls[nn][kk + 3] << 16);
    *(uint2*)&Wt[(n0 + nn) * F + kk] = o;
}

// Fused bucket + GEMM-v2, block-level split, 512 threads.
// Blocks [0, BKT_BLKS): 2048 edges -> 400 row-group LDS buckets (cap 28,
//   init -1), flush RAW bkt blob (44.8 KB) contiguous -> region[block].
//   Packed entry: (s % 25) << 14 | t; -1 = empty. Zero global atomics.
// Blocks [BKT_BLKS, +GEMM_BLKS): H = bf16(X) @ bf16(W), MFMA 16x16x32.
//   32 rows/block staged in LDS [32][264]; wave w: strip w>>2, col-group
//   w&3 (acc[4]=16 VGPR). C layout: col=lane&15, row=(lane>>4)*4+reg
//   [learn_hip m89/m91]. H store split per column plane: plane = col>>7.
__global__ void __launch_bounds__(512) k_bucket_gemm(
    const int* __restrict__ edges, int* __restrict__ region,
    const float* __restrict__ X, const unsigned short* __restrict__ Wt,
    unsigned short* __restrict__ H) {
    __shared__ union U {
        struct { int bkt[NG][BCAP]; int bcnt[NG]; } b;  // 46,400 B
        unsigned short lsA[32][264];                    // 16,896 B
    } sh;
    int tid = threadIdx.x;

    if (blockIdx.x < BKT_BLKS) {
        int probe = edges[2 * (tid & 63) + 1];
        bool is32 = __ballot(probe != 0) != 0ull;  // wave-uniform dtype detect
        for (int i = tid; i < NG; i += 512) sh.b.bcnt[i] = 0;
        int4 mone; mone.x = -1; mone.y = -1; mone.z = -1; mone.w = -1;
        int4* b4 = (int4*)&sh.b.bkt[0][0];
        for (int i = tid; i < REG_PB / 4; i += 512) b4[i] = mone;
        __syncthreads();
#pragma unroll
        for (int k = 0; k < EPB / 512; ++k) {
            int e = blockIdx.x * EPB + k * 512 + tid;
            if (e >= E) break;  // wave-uniform only in last block's tail
            int s, t;
            if (is32) { s = edges[e];     t = edges[E + e]; }
            else      { s = edges[2 * e]; t = edges[2 * E + 2 * e]; }
            if ((unsigned)s < (unsigned)N && (unsigned)t < (unsigned)N) {
                int g = s / GROWS;
                int v = ((s - g * GROWS) << 14) | t;
                int pos = atomicAdd(&sh.b.bcnt[g], 1);  // LDS atomic: cheap
                if (pos < BCAP) sh.b.bkt[g][pos] = v;
            }
        }
        __syncthreads();
        int4* dst = (int4*)(region + (size_t)blockIdx.x * REG_PB);
        for (int i = tid; i < REG_PB / 4; i += 512) dst[i] = b4[i];
        return;
    }
    // --- GEMM-v2 path: 32 rows per block ---
    int r0 = (blockIdx.x - BKT_BLKS) * 32;
    {   // stage X rows -> LDS bf16 (guard tail rows >= N)
        int row = tid >> 4, seg = tid & 15;
        if (r0 + row < N) {
            const float4* src = (const float4*)(X + (r0 + row) * F + seg * 16);
#pragma unroll
            for (int j = 0; j < 4; ++j) {
                float4 v = src[j];
                uint2 o;
                o.x = (unsigned)f2bf(v.x) | ((unsigned)f2bf(v.y) << 16);
                o.y = (unsigned)f2bf(v.z) | ((unsigned)f2bf(v.w) << 16);
                *(uint2*)&sh.lsA[row][seg * 16 + j * 4] = o;
            }
        }
    }
    __syncthreads();
    int lane = tid & 63, wv = tid >> 6;
    int sl = wv >> 2;            // strip 0/1 (rows r0+sl*16 .. +16)
    int cg = wv & 3;             // col-group (4 tiles)
    if (r0 + sl * 16 >= N) return;  // tail block: strip 1 empty
    int m = lane & 15, q = lane >> 4;
    const s8v* B = (const s8v*)(Wt + m * F + q * 8);
    f4v acc[4] = {};
#pragma unroll
    for (int kk = 0; kk < 8; ++kk) {
        s8v af = *(const s8v*)&sh.lsA[sl * 16 + m][kk * 32 + q * 8];
#pragma unroll
        for (int tt = 0; tt < 4; ++tt) {
            int t = cg * 4 + tt;
            s8v bf = B[t * 512 + kk * 4];
            acc[tt] = __builtin_amdgcn_mfma_f32_16x16x32_bf16(af, bf, acc[tt], 0, 0, 0);
        }
    }
#pragma unroll
    for (int tt = 0; tt < 4; ++tt) {
        int col = (cg * 4 + tt) * 16 + m;
        int plane = col >> 7, c128 = col & 127;
#pragma unroll
        for (int i = 0; i < 4; ++i)
            H[((size_t)plane * N + (r0 + sl * 16 + q * 4 + i)) * 128 + c128] =
                f2bf(acc[tt][i]);
    }
}

// Dedup + scan, zero global atomics, every region byte read exactly once.
// Block g: read region[j][g*28 .. +28) for all j (7 uint4, 112B chunks),
// ds_or valid entries into 25x320-word LDS bitmap; popcount + wave prefix
// -> adj/cnt. deg via byte-lane LDS counters (max 25/byte < 256), flushed
// 10KB coalesced -> part32[g].
__global__ void __launch_bounds__(512) k_fillscan(
    const int* __restrict__ region,
    int* __restrict__ adj, int* __restrict__ cnt, unsigned* __restrict__ part32) {
    __shared__ unsigned bmp[GROWS][320];  // 32,000 B
    __shared__ unsigned hist32[N / 4];    // 10,000 B
    int tid = threadIdx.x;
    {
        u4v z = {0u, 0u, 0u, 0u};
        u4v* z4 = (u4v*)&bmp[0][0];
        for (int i = tid; i < GROWS * 320 / 4; i += 512) z4[i] = z;
        u4v* h4 = (u4v*)hist32;
        for (int i = tid; i < N / 16; i += 512) h4[i] = z;
    }
    __syncthreads();

    int g = blockIdx.x;
    const u4v* reg4 = (const u4v*)region;
    for (int idx = tid; idx < BKT_BLKS * (BCAP / 4); idx += 512) {
        int j = idx / (BCAP / 4), q = idx - (BCAP / 4) * j;
        u4v v4 = reg4[(size_t)j * (REG_PB / 4) + g * (BCAP / 4) + q];
#pragma unroll
        for (int jj = 0; jj < 4; ++jj) {
            int v = (int)v4[jj];
            if (v >= 0) {
                int r = v >> 14;              // 0..24
                unsigned t = (unsigned)(v & 16383);
                atomicOr(&bmp[r][t >> 5], 1u << (t & 31));  // LDS ds_or
            }
        }
    }
    __syncthreads();

    int wave = tid >> 6, lane = tid & 63;
    for (int r = wave; r < GROWS; r += 8) {
        int s = g * GROWS + r;
        const unsigned* row = bmp[r];
        unsigned w0 = row[lane];
        unsigned w1 = row[lane + 64];
        unsigned w2 = row[lane + 128];
        unsigned w3 = row[lane + 192];
        unsigned w4 = row[lane + 256];
        int pc = __popc(w0) + __popc(w1) + __popc(w2) + __popc(w3) + __popc(w4);
        int sc = pc;
#pragma unroll
        for (int d = 1; d < 64; d <<= 1) {
            int v = __shfl_up(sc, d);
            if (lane >= d) sc += v;
        }
        int o = sc - pc;
        if (lane == 63) cnt[s] = sc < DEGCAP ? sc : DEGCAP;
        int* arow = adj + s * DEGCAP;
        unsigned wvs[5] = {w0, w1, w2, w3, w4};
#pragma unroll
        for (int j = 0; j < 5; ++j) {
            unsigned w = wvs[j];
            int base = (j * 64 + lane) * 32;
            while (w) {
                int b = __ffs(w) - 1;
                w &= w - 1;
                int t = base + b;
                if (o < DEGCAP) arow[o] = t;
                ++o;
                atomicAdd(&hist32[t >> 2], 1u << ((t & 3) * 8));  // LDS byte-lane
            }
        }
    }
    __syncthreads();
    {   // coalesced 10KB partial flush
        u4v* src = (u4v*)hist32;
        u4v* dst = (u4v*)(part32 + (size_t)g * (N / 4));
        for (int i = tid; i < N / 16; i += 512) dst[i] = src[i];
    }
}

// deg[t] = 1 (self-loop) + sum of 400 byte-lane partials. Coalesced, 4 MB,
// zero atomics.
__global__ void k_deg(const unsigned* __restrict__ part32, int* __restrict__ deg) {
    int j2 = blockIdx.x * blockDim.x + threadIdx.x;  // 0..2499
    if (j2 >= N / 4) return;
    int s0 = 1, s1 = 1, s2 = 1, s3 = 1;
#pragma unroll 8
    for (int b = 0; b < NG; ++b) {
        unsigned w = part32[(size_t)b * (N / 4) + j2];
        s0 += w & 255; s1 += (w >> 8) & 255; s2 += (w >> 16) & 255; s3 += w >> 24;
    }
    int4 o; o.x = s0; o.y = s1; o.z = s2; o.w = s3;
    *(int4*)&deg[j2 * 4] = o;
}

#define ACC8(hv, dv)                                          \
    p0 += dv * bf2f((unsigned short)(hv.x & 0xFFFF));         \
    p1 += dv * bf2f((unsigned short)(hv.x >> 16));            \
    p2 += dv * bf2f((unsigned short)(hv.y & 0xFFFF));         \
    p3 += dv * bf2f((unsigned short)(hv.y >> 16));            \
    p4 += dv * bf2f((unsigned short)(hv.z & 0xFFFF));         \
    p5 += dv * bf2f((unsigned short)(hv.z >> 16));            \
    p6 += dv * bf2f((unsigned short)(hv.w & 0xFFFF));         \
    p7 += dv * bf2f((unsigned short)(hv.w >> 16));

// Split-plane gather: 5000 blocks; plane = blk/2500 (ordered dispatch ->
// temporal phase separation; each plane's H-half = 2.56 MB, L2-resident
// per XCD). One wave per node per plane. 4 lane-groups of 16: group gq
// processes neighbor i+gq (broadcast adj/deg loads, no shfl cache, no
// c<=64 cap); half-row = 16 uint4, hl = lane&15. Reduction: shfl_xor 16,32.
// Self term added in group 0 only. Coalesced 512B half-row writes.
__global__ void k_gather(const int* __restrict__ adj, const int* __restrict__ cnt,
                         const int* __restrict__ deg,
                         const unsigned short* __restrict__ H,
                         float* __restrict__ out) {
    int wave = threadIdx.x >> 6;
    int lane = threadIdx.x & 63;
    int plane = blockIdx.x / 2500;
    int s = (blockIdx.x % 2500) * 4 + wave;  // N = 2500*4 exactly
    int gq = lane >> 4, hl = lane & 15;
    const uint4* Hp = (const uint4*)(H + (size_t)plane * N * 128);  // 16 uint4/row
    float ds = rsqrtf((float)deg[s]);
    int c = cnt[s]; if (c > DEGCAP) c = DEGCAP;
    const int* a = adj + s * DEGCAP;

    uint4 hs = Hp[s * 16 + hl];
    float p0, p1, p2, p3, p4, p5, p6, p7;
    {
        float w = (gq == 0) ? ds : 0.0f;  // self term once
        p0 = w * bf2f((unsigned short)(hs.x & 0xFFFF));
        p1 = w * bf2f((unsigned short)(hs.x >> 16));
        p2 = w * bf2f((unsigned short)(hs.y & 0xFFFF));
        p3 = w * bf2f((unsigned short)(hs.y >> 16));
        p4 = w * bf2f((unsigned short)(hs.z & 0xFFFF));
        p5 = w * bf2f((unsigned short)(hs.z >> 16));
        p6 = w * bf2f((unsigned short)(hs.w & 0xFFFF));
        p7 = w * bf2f((unsigned short)(hs.w >> 16));
    }
    for (int i = 0; i < c; i += 4) {  // 4 neighbors per iter (one per group)
        int idx = i + gq;
        int t = s; float d = 0.0f;
        if (idx < c) { t = a[idx]; d = rsqrtf((float)deg[t]); }  // broadcast loads
        uint4 h = Hp[t * 16 + hl];
        ACC8(h, d)
    }
    p0 += __shfl(p0, lane ^ 16); p1 += __shfl(p1, lane ^ 16);
    p2 += __shfl(p2, lane ^ 16); p3 += __shfl(p3, lane ^ 16);
    p4 += __shfl(p4, lane ^ 16); p5 += __shfl(p5, lane ^ 16);
    p6 += __shfl(p6, lane ^ 16); p7 += __shfl(p7, lane ^ 16);
    p0 += __shfl(p0, lane ^ 32); p1 += __shfl(p1, lane ^ 32);
    p2 += __shfl(p2, lane ^ 32); p3 += __shfl(p3, lane ^ 32);
    p4 += __shfl(p4, lane ^ 32); p5 += __shfl(p5, lane ^ 32);
    p6 += __shfl(p6, lane ^ 32); p7 += __shfl(p7, lane ^ 32);
    p0 = fmaxf(p0 * ds, 0.0f); p1 = fmaxf(p1 * ds, 0.0f);
    p2 = fmaxf(p2 * ds, 0.0f); p3 = fmaxf(p3 * ds, 0.0f);
    p4 = fmaxf(p4 * ds, 0.0f); p5 = fmaxf(p5 * ds, 0.0f);
    p6 = fmaxf(p6 * ds, 0.0f); p7 = fmaxf(p7 * ds, 0.0f);
    float* orow = out + (size_t)s * F + plane * 128;
    if (gq == 0) {
        float4 o; o.x = p0; o.y = p1; o.z = p2; o.w = p3;
        *(float4*)&orow[hl * 8] = o;
    } else if (gq == 1) {
        float4 o; o.x = p4; o.y = p5; o.z = p6; o.w = p7;
        *(float4*)&orow[hl * 8 + 4] = o;
    }
}

extern "C" void kernel_launch(void* const* d_in, const int* in_sizes, int n_in,
                              void* d_out, int out_size, void* d_ws, size_t ws_size,
                              hipStream_t stream) {
    const float* X = (const float*)d_in[0];
    const float* W = (const float*)d_in[1];
    const int* edges = (const int*)d_in[2];

    char* ws = (char*)d_ws;
    int* deg           = (int*)(ws + OFF_DEG);
    int* cnt           = (int*)(ws + OFF_CNT);
    int* adj           = (int*)(ws + OFF_ADJ);
    unsigned short* Wt = (unsigned short*)(ws + OFF_WT);
    unsigned short* H  = (unsigned short*)(ws + OFF_H);
    int* region        = (int*)(ws + OFF_REG);
    unsigned* part32   = (unsigned*)(ws + OFF_PART);

    k_pre<<<64, 256, 0, stream>>>(W, Wt);
    k_bucket_gemm<<<BKT_BLKS + GEMM_BLKS, 512, 0, stream>>>(edges, region, X, Wt, H);
    k_fillscan<<<NG, 512, 0, stream>>>(region, adj, cnt, part32);
    k_deg<<<(N / 4 + 255) / 256, 256, 0, stream>>>(part32, deg);
    k_gather<<<5000, 256, 0, stream>>>(adj, cnt, deg, H, (float*)d_out);
}

// Round 14
// 125.954 us; speedup vs baseline: 1.0928x; 1.0928x over previous
//
#include <hip/hip_runtime.h>
#include <hip/hip_bf16.h>

// GCN layer: out = relu( D^-1/2 (dedup(A) + I) D^-1/2 (X @ W) )
// N=10000, E=320000, F=256.
// Storage: fp32 X/W/out (PROVEN). Edges: int32 expected, int64 tolerated
// via per-wave ballot detect.
// Cost model (r1-r13 measured):
//  - ~300k+ device-scope atomic RMWs cost 45-50us regardless of structure
//    -> ZERO global atomics anywhere (r11/r12 architecture).
//  - Pipeline traffic-sensitive at ~5-6 TB/s effective (r12: region 24->7MB
//    bought the predicted ~10us; 137->127).
//  - r13 REGRESSION (+10.6us): split-plane gather. Dependent-load inner
//    chain (a[i]->deg->rsqrt->H) + 2x block overhead; dispatch-order L2
//    phase separation is NOT controllable from HIP. Lesson: keep the
//    register-cached shfl-broadcast gather loop.
//  - acc[16] GEMM starved regalloc (r8); GEMM-v2 = LDS-staged X + acc[4].
//  - LDS atomics cheap; block-level fusion safe (r3), thread-level not (r6).
// THIS ROUND: revert to r12 (127us best) + two surgical gather changes:
//  (1) k_deg emits dinv = rsqrtf(deg) (fp32) -- gather drops a dependent
//      int-load+cvt+rsqrt per neighbor (bit-identical math).
//  (2) gather inner loop 8 rows in flight per half-wave (i += 16): mean
//      c~32 -> 2 dependent iterations instead of 4 (latency-bound fix).
// 5 launches: k_pre(Wt) -> k_bucket_gemm -> k_fillscan -> k_deg -> k_gather.
//
// ws layout (bytes), ~20.2 MB (ws is 256 MiB):
//   dinv   f32[N]           @ 0           (rsqrt(deg), written by k_deg)
//   cnt    i32[N]           @ 40,960
//   adj    i32[N*96]        @ 81,920
//   Wt     bf16[F*F]        @ 3,921,920
//   H      bf16[N*F]        @ 4,052,992
//   region i32[157*11200]   @ 9,172,992   (7.03 MB bucket blobs)
//   part32 u32[400*2500]    @ 16,206,592  (4 MB byte-lane deg partials)

constexpr int N = 10000;
constexpr int E = 320000;
constexpr int F = 256;
constexpr int DEGCAP = 96;   // Poisson(32): P(any deduped degree >= 96) ~ 1e-16
constexpr int GROWS = 25;    // rows per group (fillscan block)
constexpr int NG = N / GROWS;        // 400 groups
constexpr int EPB = 2048;    // edges per bucket block
constexpr int BCAP = 28;     // Poisson(5.12): P(>28) ~ 3e-12 x 63k pairs ~ 2e-7
constexpr int REG_PB = NG * BCAP;    // 11200 ints per source block

constexpr int BKT_BLKS  = (E + EPB - 1) / EPB;  // 157 (last block 1536 edges)
constexpr int GEMM_BLKS = (N + 31) / 32;        // 313 (last block 16 rows)

constexpr size_t OFF_DINV = 0;
constexpr size_t OFF_CNT  = 40960;
constexpr size_t OFF_ADJ  = 81920;
constexpr size_t OFF_WT   = OFF_ADJ + 4ull * N * DEGCAP;        // 3,921,920
constexpr size_t OFF_H    = OFF_WT + 2ull * F * F;              // 4,052,992
constexpr size_t OFF_REG  = OFF_H + 2ull * N * F;               // 9,172,992
constexpr size_t OFF_PART = OFF_REG + 4ull * BKT_BLKS * REG_PB; // 16,206,592

typedef short s8v __attribute__((ext_vector_type(8)));   // 8 bf16 = 4 VGPRs
typedef float f4v __attribute__((ext_vector_type(4)));   // MFMA accumulator
typedef unsigned u4v __attribute__((ext_vector_type(4)));

__device__ __forceinline__ float bf2f(unsigned short u) {
    union { unsigned u; float f; } c; c.u = (unsigned)u << 16; return c.f;
}
__device__ __forceinline__ unsigned short f2bf(float f) {
    union { __hip_bfloat16 b; unsigned short s; } c; c.b = __float2bfloat16(f); return c.s;
}

// 64 blocks: W (fp32) -> Wt (bf16, transposed). Region needs no prefill
// (raw blob flush writes every byte); cnt/dinv/part written downstream.
__global__ void k_pre(const float* __restrict__ W, unsigned short* __restrict__ Wt) {
    __shared__ unsigned short ls[4][F];
    int n0 = blockIdx.x * 4;
    int k = threadIdx.x;
    float4 v = *(const float4*)&W[k * F + n0];
    ls[0][k] = f2bf(v.x); ls[1][k] = f2bf(v.y);
    ls[2][k] = f2bf(v.z); ls[3][k] = f2bf(v.w);
    __syncthreads();
    int nn = threadIdx.x >> 6;
    int kk = (threadIdx.x & 63) * 4;
    uint2 o;
    o.x = (unsigned)ls[nn][kk]     | ((unsigned)ls[nn][kk + 1] << 16);
    o.y = (unsigned)ls[nn][kk + 2] | ((unsigned)ls[nn][kk + 3] << 16);
    *(uint2*)&Wt[(n0 + nn) * F + kk] = o;
}

// Fused bucket + GEMM-v2, block-level split, 512 threads (r12-proven).
// Blocks [0, BKT_BLKS): 2048 edges -> 400 row-group LDS buckets (cap 28,
//   init -1), flush RAW bkt blob (44.8 KB) contiguous -> region[block].
//   Packed entry: (s % 25) << 14 | t; -1 = empty. Zero global atomics.
// Blocks [BKT_BLKS, +GEMM_BLKS): H = bf16(X) @ bf16(W), MFMA 16x16x32.
//   32 rows/block staged in LDS [32][264]; wave w: strip w>>2, col-group
//   w&3 (acc[4]=16 VGPR). C layout: col=lane&15, row=(lane>>4)*4+reg
//   [learn_hip m89/m91].
__global__ void __launch_bounds__(512) k_bucket_gemm(
    const int* __restrict__ edges, int* __restrict__ region,
    const float* __restrict__ X, const unsigned short* __restrict__ Wt,
    unsigned short* __restrict__ H) {
    __shared__ union U {
        struct { int bkt[NG][BCAP]; int bcnt[NG]; } b;  // 46,400 B
        unsigned short lsA[32][264];                    // 16,896 B
    } sh;
    int tid = threadIdx.x;

    if (blockIdx.x < BKT_BLKS) {
        int probe = edges[2 * (tid & 63) + 1];
        bool is32 = __ballot(probe != 0) != 0ull;  // wave-uniform dtype detect
        for (int i = tid; i < NG; i += 512) sh.b.bcnt[i] = 0;
        int4 mone; mone.x = -1; mone.y = -1; mone.z = -1; mone.w = -1;
        int4* b4 = (int4*)&sh.b.bkt[0][0];
        for (int i = tid; i < REG_PB / 4; i += 512) b4[i] = mone;
        __syncthreads();
#pragma unroll
        for (int k = 0; k < EPB / 512; ++k) {
            int e = blockIdx.x * EPB + k * 512 + tid;
            if (e >= E) break;  // wave-uniform only in last block's tail
            int s, t;
            if (is32) { s = edges[e];     t = edges[E + e]; }
            else      { s = edges[2 * e]; t = edges[2 * E + 2 * e]; }
            if ((unsigned)s < (unsigned)N && (unsigned)t < (unsigned)N) {
                int g = s / GROWS;
                int v = ((s - g * GROWS) << 14) | t;
                int pos = atomicAdd(&sh.b.bcnt[g], 1);  // LDS atomic: cheap
                if (pos < BCAP) sh.b.bkt[g][pos] = v;
            }
        }
        __syncthreads();
        int4* dst = (int4*)(region + (size_t)blockIdx.x * REG_PB);
        for (int i = tid; i < REG_PB / 4; i += 512) dst[i] = b4[i];
        return;
    }
    // --- GEMM-v2 path: 32 rows per block ---
    int r0 = (blockIdx.x - BKT_BLKS) * 32;
    {   // stage X rows -> LDS bf16 (guard tail rows >= N)
        int row = tid >> 4, seg = tid & 15;
        if (r0 + row < N) {
            const float4* src = (const float4*)(X + (r0 + row) * F + seg * 16);
#pragma unroll
            for (int j = 0; j < 4; ++j) {
                float4 v = src[j];
                uint2 o;
                o.x = (unsigned)f2bf(v.x) | ((unsigned)f2bf(v.y) << 16);
                o.y = (unsigned)f2bf(v.z) | ((unsigned)f2bf(v.w) << 16);
                *(uint2*)&sh.lsA[row][seg * 16 + j * 4] = o;
            }
        }
    }
    __syncthreads();
    int lane = tid & 63, wv = tid >> 6;
    int sl = wv >> 2;            // strip 0/1 (rows r0+sl*16 .. +16)
    int cg = wv & 3;             // col-group (4 tiles)
    if (r0 + sl * 16 >= N) return;  // tail block: strip 1 empty
    int m = lane & 15, q = lane >> 4;
    const s8v* B = (const s8v*)(Wt + m * F + q * 8);
    f4v acc[4] = {};
#pragma unroll
    for (int kk = 0; kk < 8; ++kk) {
        s8v af = *(const s8v*)&sh.lsA[sl * 16 + m][kk * 32 + q * 8];
#pragma unroll
        for (int tt = 0; tt < 4; ++tt) {
            int t = cg * 4 + tt;
            s8v bf = B[t * 512 + kk * 4];
            acc[tt] = __builtin_amdgcn_mfma_f32_16x16x32_bf16(af, bf, acc[tt], 0, 0, 0);
        }
    }
#pragma unroll
    for (int tt = 0; tt < 4; ++tt) {
        int col = (cg * 4 + tt) * 16 + m;
#pragma unroll
        for (int i = 0; i < 4; ++i)
            H[(r0 + sl * 16 + q * 4 + i) * F + col] = f2bf(acc[tt][i]);
    }
}

// Dedup + scan, zero global atomics, every region byte read exactly once
// (r12-proven). Block g: read region[j][g*28 .. +28) for all j (7 uint4,
// 112B chunks), ds_or into 25x320-word LDS bitmap; popcount + wave prefix
// -> adj/cnt. deg via byte-lane LDS counters (max 25/byte < 256), flushed
// 10KB coalesced -> part32[g].
__global__ void __launch_bounds__(512) k_fillscan(
    const int* __restrict__ region,
    int* __restrict__ adj, int* __restrict__ cnt, unsigned* __restrict__ part32) {
    __shared__ unsigned bmp[GROWS][320];  // 32,000 B
    __shared__ unsigned hist32[N / 4];    // 10,000 B
    int tid = threadIdx.x;
    {
        u4v z = {0u, 0u, 0u, 0u};
        u4v* z4 = (u4v*)&bmp[0][0];
        for (int i = tid; i < GROWS * 320 / 4; i += 512) z4[i] = z;
        u4v* h4 = (u4v*)hist32;
        for (int i = tid; i < N / 16; i += 512) h4[i] = z;
    }
    __syncthreads();

    int g = blockIdx.x;
    const u4v* reg4 = (const u4v*)region;
    for (int idx = tid; idx < BKT_BLKS * (BCAP / 4); idx += 512) {
        int j = idx / (BCAP / 4), q = idx - (BCAP / 4) * j;
        u4v v4 = reg4[(size_t)j * (REG_PB / 4) + g * (BCAP / 4) + q];
#pragma unroll
        for (int jj = 0; jj < 4; ++jj) {
            int v = (int)v4[jj];
            if (v >= 0) {
                int r = v >> 14;              // 0..24
                unsigned t = (unsigned)(v & 16383);
                atomicOr(&bmp[r][t >> 5], 1u << (t & 31));  // LDS ds_or
            }
        }
    }
    __syncthreads();

    int wave = tid >> 6, lane = tid & 63;
    for (int r = wave; r < GROWS; r += 8) {
        int s = g * GROWS + r;
        const unsigned* row = bmp[r];
        unsigned w0 = row[lane];
        unsigned w1 = row[lane + 64];
        unsigned w2 = row[lane + 128];
        unsigned w3 = row[lane + 192];
        unsigned w4 = row[lane + 256];
        int pc = __popc(w0) + __popc(w1) + __popc(w2) + __popc(w3) + __popc(w4);
        int sc = pc;
#pragma unroll
        for (int d = 1; d < 64; d <<= 1) {
            int v = __shfl_up(sc, d);
            if (lane >= d) sc += v;
        }
        int o = sc - pc;
        if (lane == 63) cnt[s] = sc < DEGCAP ? sc : DEGCAP;
        int* arow = adj + s * DEGCAP;
        unsigned wvs[5] = {w0, w1, w2, w3, w4};
#pragma unroll
        for (int j = 0; j < 5; ++j) {
            unsigned w = wvs[j];
            int base = (j * 64 + lane) * 32;
            while (w) {
                int b = __ffs(w) - 1;
                w &= w - 1;
                int t = base + b;
                if (o < DEGCAP) arow[o] = t;
                ++o;
                atomicAdd(&hist32[t >> 2], 1u << ((t & 3) * 8));  // LDS byte-lane
            }
        }
    }
    __syncthreads();
    {   // coalesced 10KB partial flush
        u4v* src = (u4v*)hist32;
        u4v* dst = (u4v*)(part32 + (size_t)g * (N / 4));
        for (int i = tid; i < N / 16; i += 512) dst[i] = src[i];
    }
}

// dinv[t] = rsqrt(1 + sum of 400 byte-lane partials). Coalesced, 4 MB,
// zero atomics. Emitting rsqrt here (instead of per-use in gather) removes
// a dependent int-load+cvt+rsqrt per neighbor visit (bit-identical math).
__global__ void k_deg(const unsigned* __restrict__ part32, float* __restrict__ dinv) {
    int j2 = blockIdx.x * blockDim.x + threadIdx.x;  // 0..2499
    if (j2 >= N / 4) return;
    int s0 = 1, s1 = 1, s2 = 1, s3 = 1;
#pragma unroll 8
    for (int b = 0; b < NG; ++b) {
        unsigned w = part32[(size_t)b * (N / 4) + j2];
        s0 += w & 255; s1 += (w >> 8) & 255; s2 += (w >> 16) & 255; s3 += w >> 24;
    }
    float4 o;
    o.x = rsqrtf((float)s0); o.y = rsqrtf((float)s1);
    o.z = rsqrtf((float)s2); o.w = rsqrtf((float)s3);
    *(float4*)&dinv[j2 * 4] = o;
}

#define ACC8(hv, dv)                                          \
    p0 += dv * bf2f((unsigned short)(hv.x & 0xFFFF));         \
    p1 += dv * bf2f((unsigned short)(hv.x >> 16));            \
    p2 += dv * bf2f((unsigned short)(hv.y & 0xFFFF));         \
    p3 += dv * bf2f((unsigned short)(hv.y >> 16));            \
    p4 += dv * bf2f((unsigned short)(hv.z & 0xFFFF));         \
    p5 += dv * bf2f((unsigned short)(hv.z >> 16));            \
    p6 += dv * bf2f((unsigned short)(hv.w & 0xFFFF));         \
    p7 += dv * bf2f((unsigned short)(hv.w >> 16));

// Proven gather (r12 structure: register-cached tl/dl + shfl broadcast),
// upgraded: dinv fp32 loads (no per-neighbor rsqrt) and 8 rows in flight
// per half-wave (i += 16; mean c~32 -> 2 dependent iterations, was 4).
// Lanes >= c carry dl=0 -> zero-weight padding rows (t=0), harmless.
__global__ void k_gather(const int* __restrict__ adj, const int* __restrict__ cnt,
                         const float* __restrict__ dinv,
                         const unsigned short* __restrict__ H,
                         float* __restrict__ out) {
    int wave = threadIdx.x >> 6;
    int lane = threadIdx.x & 63;
    int s = blockIdx.x * 4 + wave;  // N = 2500*4 exactly
    int half = lane >> 5, hl = lane & 31;
    const uint4* H16 = (const uint4*)H;  // 8 bf16 per uint4; row stride 32
    float ds = dinv[s];
    int c = cnt[s]; if (c > DEGCAP) c = DEGCAP;
    const int* a = adj + s * DEGCAP;
    int tl = 0; float dl = 0.0f;
    if (lane < c) { tl = a[lane]; dl = dinv[tl]; }

    uint4 hs = H16[s * 32 + hl];
    float p0, p1, p2, p3, p4, p5, p6, p7;
    {
        float w = half ? 0.0f : ds;  // self term once (half 0 only)
        p0 = w * bf2f((unsigned short)(hs.x & 0xFFFF));
        p1 = w * bf2f((unsigned short)(hs.x >> 16));
        p2 = w * bf2f((unsigned short)(hs.y & 0xFFFF));
        p3 = w * bf2f((unsigned short)(hs.y >> 16));
        p4 = w * bf2f((unsigned short)(hs.z & 0xFFFF));
        p5 = w * bf2f((unsigned short)(hs.z >> 16));
        p6 = w * bf2f((unsigned short)(hs.w & 0xFFFF));
        p7 = w * bf2f((unsigned short)(hs.w >> 16));
    }
    int cc = c < 64 ? c : 64;
    for (int i = 0; i < cc; i += 16) {  // 8 pairs = 16 neighbors per iter
        int i0 = i + half,      i1 = i + 2 + half;
        int i2 = i + 4 + half,  i3 = i + 6 + half;
        int i4 = i + 8 + half,  i5 = i + 10 + half;
        int i6 = i + 12 + half, i7 = i + 14 + half;
        int t0 = __shfl(tl, i0), t1 = __shfl(tl, i1);
        int t2 = __shfl(tl, i2), t3 = __shfl(tl, i3);
        int t4 = __shfl(tl, i4), t5 = __shfl(tl, i5);
        int t6 = __shfl(tl, i6), t7 = __shfl(tl, i7);
        float d0 = __shfl(dl, i0), d1 = __shfl(dl, i1);
        float d2 = __shfl(dl, i2), d3 = __shfl(dl, i3);
        float d4 = __shfl(dl, i4), d5 = __shfl(dl, i5);
        float d6 = __shfl(dl, i6), d7 = __shfl(dl, i7);
        uint4 h0 = H16[t0 * 32 + hl];
        uint4 h1 = H16[t1 * 32 + hl];
        uint4 h2 = H16[t2 * 32 + hl];
        uint4 h3 = H16[t3 * 32 + hl];
        uint4 h4 = H16[t4 * 32 + hl];
        uint4 h5 = H16[t5 * 32 + hl];
        uint4 h6 = H16[t6 * 32 + hl];
        uint4 h7 = H16[t7 * 32 + hl];
        ACC8(h0, d0) ACC8(h1, d1) ACC8(h2, d2) ACC8(h3, d3)
        ACC8(h4, d4) ACC8(h5, d5) ACC8(h6, d6) ACC8(h7, d7)
    }
    for (int i = 64; i < c; ++i) {  // rare: deduped degree > 64
        int t = a[i];
        float d = half ? 0.0f : dinv[t];
        uint4 h = H16[t * 32 + hl];
        ACC8(h, d)
    }
    p0 += __shfl(p0, lane ^ 32); p1 += __shfl(p1, lane ^ 32);
    p2 += __shfl(p2, lane ^ 32); p3 += __shfl(p3, lane ^ 32);
    p4 += __shfl(p4, lane ^ 32); p5 += __shfl(p5, lane ^ 32);
    p6 += __shfl(p6, lane ^ 32); p7 += __shfl(p7, lane ^ 32);
    p0 = fmaxf(p0 * ds, 0.0f); p1 = fmaxf(p1 * ds, 0.0f);
    p2 = fmaxf(p2 * ds, 0.0f); p3 = fmaxf(p3 * ds, 0.0f);
    p4 = fmaxf(p4 * ds, 0.0f); p5 = fmaxf(p5 * ds, 0.0f);
    p6 = fmaxf(p6 * ds, 0.0f); p7 = fmaxf(p7 * ds, 0.0f);
    float4 o;
    if (half) { o.x = p4; o.y = p5; o.z = p6; o.w = p7; }
    else      { o.x = p0; o.y = p1; o.z = p2; o.w = p3; }
    ((float4*)out)[s * 64 + hl * 2 + half] = o;
}

extern "C" void kernel_launch(void* const* d_in, const int* in_sizes, int n_in,
                              void* d_out, int out_size, void* d_ws, size_t ws_size,
                              hipStream_t stream) {
    const float* X = (const float*)d_in[0];
    const float* W = (const float*)d_in[1];
    const int* edges = (const int*)d_in[2];

    char* ws = (char*)d_ws;
    float* dinv        = (float*)(ws + OFF_DINV);
    int* cnt           = (int*)(ws + OFF_CNT);
    int* adj           = (int*)(ws + OFF_ADJ);
    unsigned short* Wt = (unsigned short*)(ws + OFF_WT);
    unsigned short* H  = (unsigned short*)(ws + OFF_H);
    int* region        = (int*)(ws + OFF_REG);
    unsigned* part32   = (unsigned*)(ws + OFF_PART);

    k_pre<<<64, 256, 0, stream>>>(W, Wt);
    k_bucket_gemm<<<BKT_BLKS + GEMM_BLKS, 512, 0, stream>>>(edges, region, X, Wt, H);
    k_fillscan<<<NG, 512, 0, stream>>>(region, adj, cnt, part32);
    k_deg<<<(N / 4 + 255) / 256, 256, 0, stream>>>(part32, dinv);
    k_gather<<<N / 4, 256, 0, stream>>>(adj, cnt, dinv, H, (float*)d_out);
}

// Round 15
// 119.872 us; speedup vs baseline: 1.1482x; 1.0507x over previous
//
#include <hip/hip_runtime.h>
#include <hip/hip_bf16.h>

// GCN layer: out = relu( D^-1/2 (dedup(A) + I) D^-1/2 (X @ W) )
// N=10000, E=320000, F=256.
// Storage: fp32 X/W/out (PROVEN). Edges: int32 expected, int64 tolerated
// via per-wave ballot detect.
// Cost model (r1-r14 measured):
//  - ~300k+ device-scope atomic RMWs cost 45-50us regardless of structure
//    -> ZERO global atomics anywhere (r11+ architecture).
//  - Traffic-sensitive at ~5-6 TB/s effective (r12: region 24->7MB = -10us).
//  - r13: dependent-load gather chain + dispatch-order L2 schemes = regression.
//  - r14: gather latency fixes = null -> gather is at its BW floor (~165MB
//    L3-resident logical reads). Remaining lever: serial chain depth.
//  - acc[16] GEMM starved regalloc (r8); GEMM-v2 = LDS-staged X + acc[4].
//  - LDS atomics cheap; BLOCK-level fusion safe (r3), thread-level not (r6).
// THIS ROUND: chain 5 -> 4 launches with two block-level fusions along the
// true DAG (GEMM needs only Wt; fillscan needs only region):
//   K1 = pre(32 blks, Wt) + bucket(157 blks)   [independent, overlap]
//   K2 = fillscan(400 blks) + GEMM(313 blks)   [independent, overlap:
//        GEMM's MFMA/VMEM pipes co-schedule with fillscan's LDS work, m114]
//   K3 = deg   K4 = gather (r14-proven, unchanged)
//
// ws layout (bytes), ~20.2 MB (ws is 256 MiB):
//   dinv   f32[N]           @ 0           (rsqrt(deg), written by k_deg)
//   cnt    i32[N]           @ 40,960
//   adj    i32[N*96]        @ 81,920
//   Wt     bf16[F*F]        @ 3,921,920
//   H      bf16[N*F]        @ 4,052,992
//   region i32[157*11200]   @ 9,172,992   (7.03 MB bucket blobs)
//   part32 u32[400*2500]    @ 16,206,592  (4 MB byte-lane deg partials)

constexpr int N = 10000;
constexpr int E = 320000;
constexpr int F = 256;
constexpr int DEGCAP = 96;   // Poisson(32): P(any deduped degree >= 96) ~ 1e-16
constexpr int GROWS = 25;    // rows per group (fillscan block)
constexpr int NG = N / GROWS;        // 400 groups
constexpr int EPB = 2048;    // edges per bucket block
constexpr int BCAP = 28;     // Poisson(5.12): P(>28) ~ 3e-12 x 63k pairs ~ 2e-7
constexpr int REG_PB = NG * BCAP;    // 11200 ints per source block

constexpr int PRE_BLKS  = 32;                   // 8 Wt rows per 512-thr block
constexpr int BKT_BLKS  = (E + EPB - 1) / EPB;  // 157 (last block 1536 edges)
constexpr int GEMM_BLKS = (N + 31) / 32;        // 313 (last block 16 rows)

constexpr size_t OFF_DINV = 0;
constexpr size_t OFF_CNT  = 40960;
constexpr size_t OFF_ADJ  = 81920;
constexpr size_t OFF_WT   = OFF_ADJ + 4ull * N * DEGCAP;        // 3,921,920
constexpr size_t OFF_H    = OFF_WT + 2ull * F * F;              // 4,052,992
constexpr size_t OFF_REG  = OFF_H + 2ull * N * F;               // 9,172,992
constexpr size_t OFF_PART = OFF_REG + 4ull * BKT_BLKS * REG_PB; // 16,206,592

typedef short s8v __attribute__((ext_vector_type(8)));   // 8 bf16 = 4 VGPRs
typedef float f4v __attribute__((ext_vector_type(4)));   // MFMA accumulator
typedef unsigned u4v __attribute__((ext_vector_type(4)));

__device__ __forceinline__ float bf2f(unsigned short u) {
    union { unsigned u; float f; } c; c.u = (unsigned)u << 16; return c.f;
}
__device__ __forceinline__ unsigned short f2bf(float f) {
    union { __hip_bfloat16 b; unsigned short s; } c; c.b = __float2bfloat16(f); return c.s;
}

// K1: fused pre + bucket, block-level split, 512 threads.
// Blocks [0, PRE_BLKS): W (fp32) -> Wt (bf16, transposed), 8 rows/block.
// Blocks [PRE_BLKS, +BKT_BLKS): 2048 edges -> 400 row-group LDS buckets
//   (cap 28, init -1), flush RAW bkt blob (44.8 KB) contiguous ->
//   region[block]. Packed entry: (s % 25) << 14 | t; -1 = empty.
//   Zero global atomics. Region needs no prefill (blob writes every byte).
__global__ void __launch_bounds__(512) k_pre_bucket(
    const float* __restrict__ W, unsigned short* __restrict__ Wt,
    const int* __restrict__ edges, int* __restrict__ region) {
    __shared__ union U {
        struct { int bkt[NG][BCAP]; int bcnt[NG]; } b;  // 46,400 B
        unsigned short ls[8][F];                        //  4,096 B
    } sh;
    int tid = threadIdx.x;

    if (blockIdx.x < PRE_BLKS) {
        // --- pre path: Wt rows n0..n0+7 ---
        int n0 = blockIdx.x * 8;
        int sub = tid >> 8;      // 0/1: cols n0+sub*4 .. +4
        int k = tid & 255;
        float4 v = *(const float4*)&W[k * F + n0 + sub * 4];
        sh.ls[sub * 4 + 0][k] = f2bf(v.x);
        sh.ls[sub * 4 + 1][k] = f2bf(v.y);
        sh.ls[sub * 4 + 2][k] = f2bf(v.z);
        sh.ls[sub * 4 + 3][k] = f2bf(v.w);
        __syncthreads();
        int rr = tid >> 6;           // 0..7
        int kk = (tid & 63) * 4;
        uint2 o;
        o.x = (unsigned)sh.ls[rr][kk]     | ((unsigned)sh.ls[rr][kk + 1] << 16);
        o.y = (unsigned)sh.ls[rr][kk + 2] | ((unsigned)sh.ls[rr][kk + 3] << 16);
        *(uint2*)&Wt[(n0 + rr) * F + kk] = o;
        return;
    }
    // --- bucket path ---
    int bb = blockIdx.x - PRE_BLKS;
    int probe = edges[2 * (tid & 63) + 1];
    bool is32 = __ballot(probe != 0) != 0ull;  // wave-uniform dtype detect
    for (int i = tid; i < NG; i += 512) sh.b.bcnt[i] = 0;
    int4 mone; mone.x = -1; mone.y = -1; mone.z = -1; mone.w = -1;
    int4* b4 = (int4*)&sh.b.bkt[0][0];
    for (int i = tid; i < REG_PB / 4; i += 512) b4[i] = mone;
    __syncthreads();
#pragma unroll
    for (int k = 0; k < EPB / 512; ++k) {
        int e = bb * EPB + k * 512 + tid;
        if (e >= E) break;  // wave-uniform only in last block's tail
        int s, t;
        if (is32) { s = edges[e];     t = edges[E + e]; }
        else      { s = edges[2 * e]; t = edges[2 * E + 2 * e]; }
        if ((unsigned)s < (unsigned)N && (unsigned)t < (unsigned)N) {
            int g = s / GROWS;
            int v = ((s - g * GROWS) << 14) | t;
            int pos = atomicAdd(&sh.b.bcnt[g], 1);  // LDS atomic: cheap
            if (pos < BCAP) sh.b.bkt[g][pos] = v;
        }
    }
    __syncthreads();
    int4* dst = (int4*)(region + (size_t)bb * REG_PB);
    for (int i = tid; i < REG_PB / 4; i += 512) dst[i] = b4[i];
}

// K2: fused fillscan + GEMM-v2, block-level split, 512 threads.
// Blocks [0, NG): dedup+scan (needs region). Block g reads
//   region[j][g*28 .. +28) for all j (7 uint4, 112B chunks; every region
//   byte read exactly once), ds_or into 25x320-word LDS bitmap; popcount +
//   wave prefix -> adj/cnt. deg via byte-lane LDS counters (max 25/byte),
//   flushed 10KB coalesced -> part32[g]. Zero global atomics.
// Blocks [NG, +GEMM_BLKS): H = bf16(X) @ bf16(W) (needs Wt), MFMA 16x16x32.
//   32 rows/block staged in LDS [32][264]; wave w: strip w>>2, col-group
//   w&3 (acc[4]=16 VGPR; r8: acc[16] starved regalloc). C layout:
//   col=lane&15, row=(lane>>4)*4+reg [learn_hip m89/m91].
__global__ void __launch_bounds__(512) k_fillscan_gemm(
    const int* __restrict__ region,
    int* __restrict__ adj, int* __restrict__ cnt, unsigned* __restrict__ part32,
    const float* __restrict__ X, const unsigned short* __restrict__ Wt,
    unsigned short* __restrict__ H) {
    __shared__ union U {
        struct { unsigned bmp[GROWS][320]; unsigned hist32[N / 4]; } f;  // 42,000 B
        unsigned short lsA[32][264];                                     // 16,896 B
    } sh;
    int tid = threadIdx.x;

    if (blockIdx.x < NG) {
        // --- fillscan path ---
        {
            u4v z = {0u, 0u, 0u, 0u};
            u4v* z4 = (u4v*)&sh.f.bmp[0][0];
            for (int i = tid; i < GROWS * 320 / 4; i += 512) z4[i] = z;
            u4v* h4 = (u4v*)sh.f.hist32;
            for (int i = tid; i < N / 16; i += 512) h4[i] = z;
        }
        __syncthreads();

        int g = blockIdx.x;
        const u4v* reg4 = (const u4v*)region;
        for (int idx = tid; idx < BKT_BLKS * (BCAP / 4); idx += 512) {
            int j = idx / (BCAP / 4), q = idx - (BCAP / 4) * j;
            u4v v4 = reg4[(size_t)j * (REG_PB / 4) + g * (BCAP / 4) + q];
#pragma unroll
            for (int jj = 0; jj < 4; ++jj) {
                int v = (int)v4[jj];
                if (v >= 0) {
                    int r = v >> 14;              // 0..24
                    unsigned t = (unsigned)(v & 16383);
                    atomicOr(&sh.f.bmp[r][t >> 5], 1u << (t & 31));  // LDS ds_or
                }
            }
        }
        __syncthreads();

        int wave = tid >> 6, lane = tid & 63;
        for (int r = wave; r < GROWS; r += 8) {
            int s = g * GROWS + r;
            const unsigned* row = sh.f.bmp[r];
            unsigned w0 = row[lane];
            unsigned w1 = row[lane + 64];
            unsigned w2 = row[lane + 128];
            unsigned w3 = row[lane + 192];
            unsigned w4 = row[lane + 256];
            int pc = __popc(w0) + __popc(w1) + __popc(w2) + __popc(w3) + __popc(w4);
            int sc = pc;
#pragma unroll
            for (int d = 1; d < 64; d <<= 1) {
                int v = __shfl_up(sc, d);
                if (lane >= d) sc += v;
            }
            int o = sc - pc;
            if (lane == 63) cnt[s] = sc < DEGCAP ? sc : DEGCAP;
            int* arow = adj + s * DEGCAP;
            unsigned wvs[5] = {w0, w1, w2, w3, w4};
#pragma unroll
            for (int j = 0; j < 5; ++j) {
                unsigned w = wvs[j];
                int base = (j * 64 + lane) * 32;
                while (w) {
                    int b = __ffs(w) - 1;
                    w &= w - 1;
                    int t = base + b;
                    if (o < DEGCAP) arow[o] = t;
                    ++o;
                    atomicAdd(&sh.f.hist32[t >> 2], 1u << ((t & 3) * 8));  // LDS byte-lane
                }
            }
        }
        __syncthreads();
        {   // coalesced 10KB partial flush
            u4v* src = (u4v*)sh.f.hist32;
            u4v* dst = (u4v*)(part32 + (size_t)g * (N / 4));
            for (int i = tid; i < N / 16; i += 512) dst[i] = src[i];
        }
        return;
    }
    // --- GEMM-v2 path: 32 rows per block ---
    int r0 = (blockIdx.x - NG) * 32;
    {   // stage X rows -> LDS bf16 (guard tail rows >= N)
        int row = tid >> 4, seg = tid & 15;
        if (r0 + row < N) {
            const float4* src = (const float4*)(X + (r0 + row) * F + seg * 16);
#pragma unroll
            for (int j = 0; j < 4; ++j) {
                float4 v = src[j];
                uint2 o;
                o.x = (unsigned)f2bf(v.x) | ((unsigned)f2bf(v.y) << 16);
                o.y = (unsigned)f2bf(v.z) | ((unsigned)f2bf(v.w) << 16);
                *(uint2*)&sh.lsA[row][seg * 16 + j * 4] = o;
            }
        }
    }
    __syncthreads();
    int lane = tid & 63, wv = tid >> 6;
    int sl = wv >> 2;            // strip 0/1 (rows r0+sl*16 .. +16)
    int cg = wv & 3;             // col-group (4 tiles)
    if (r0 + sl * 16 >= N) return;  // tail block: strip 1 empty
    int m = lane & 15, q = lane >> 4;
    const s8v* B = (const s8v*)(Wt + m * F + q * 8);
    f4v acc[4] = {};
#pragma unroll
    for (int kk = 0; kk < 8; ++kk) {
        s8v af = *(const s8v*)&sh.lsA[sl * 16 + m][kk * 32 + q * 8];
#pragma unroll
        for (int tt = 0; tt < 4; ++tt) {
            int t = cg * 4 + tt;
            s8v bf = B[t * 512 + kk * 4];
            acc[tt] = __builtin_amdgcn_mfma_f32_16x16x32_bf16(af, bf, acc[tt], 0, 0, 0);
        }
    }
#pragma unroll
    for (int tt = 0; tt < 4; ++tt) {
        int col = (cg * 4 + tt) * 16 + m;
#pragma unroll
        for (int i = 0; i < 4; ++i)
            H[(r0 + sl * 16 + q * 4 + i) * F + col] = f2bf(acc[tt][i]);
    }
}

// dinv[t] = rsqrt(1 + sum of 400 byte-lane partials). Coalesced, 4 MB,
// zero atomics. Emitting rsqrt here removes a dependent load+cvt+rsqrt per
// neighbor visit in gather (bit-identical math).
__global__ void k_deg(const unsigned* __restrict__ part32, float* __restrict__ dinv) {
    int j2 = blockIdx.x * blockDim.x + threadIdx.x;  // 0..2499
    if (j2 >= N / 4) return;
    int s0 = 1, s1 = 1, s2 = 1, s3 = 1;
#pragma unroll 8
    for (int b = 0; b < NG; ++b) {
        unsigned w = part32[(size_t)b * (N / 4) + j2];
        s0 += w & 255; s1 += (w >> 8) & 255; s2 += (w >> 16) & 255; s3 += w >> 24;
    }
    float4 o;
    o.x = rsqrtf((float)s0); o.y = rsqrtf((float)s1);
    o.z = rsqrtf((float)s2); o.w = rsqrtf((float)s3);
    *(float4*)&dinv[j2 * 4] = o;
}

#define ACC8(hv, dv)                                          \
    p0 += dv * bf2f((unsigned short)(hv.x & 0xFFFF));         \
    p1 += dv * bf2f((unsigned short)(hv.x >> 16));            \
    p2 += dv * bf2f((unsigned short)(hv.y & 0xFFFF));         \
    p3 += dv * bf2f((unsigned short)(hv.y >> 16));            \
    p4 += dv * bf2f((unsigned short)(hv.z & 0xFFFF));         \
    p5 += dv * bf2f((unsigned short)(hv.z >> 16));            \
    p6 += dv * bf2f((unsigned short)(hv.w & 0xFFFF));         \
    p7 += dv * bf2f((unsigned short)(hv.w >> 16));

// r14-proven gather: register-cached tl/dl + shfl broadcast, dinv fp32
// loads, 8 rows in flight per half-wave. Lanes >= c carry dl=0 padding.
__global__ void k_gather(const int* __restrict__ adj, const int* __restrict__ cnt,
                         const float* __restrict__ dinv,
                         const unsigned short* __restrict__ H,
                         float* __restrict__ out) {
    int wave = threadIdx.x >> 6;
    int lane = threadIdx.x & 63;
    int s = blockIdx.x * 4 + wave;  // N = 2500*4 exactly
    int half = lane >> 5, hl = lane & 31;
    const uint4* H16 = (const uint4*)H;  // 8 bf16 per uint4; row stride 32
    float ds = dinv[s];
    int c = cnt[s]; if (c > DEGCAP) c = DEGCAP;
    const int* a = adj + s * DEGCAP;
    int tl = 0; float dl = 0.0f;
    if (lane < c) { tl = a[lane]; dl = dinv[tl]; }

    uint4 hs = H16[s * 32 + hl];
    float p0, p1, p2, p3, p4, p5, p6, p7;
    {
        float w = half ? 0.0f : ds;  // self term once (half 0 only)
        p0 = w * bf2f((unsigned short)(hs.x & 0xFFFF));
        p1 = w * bf2f((unsigned short)(hs.x >> 16));
        p2 = w * bf2f((unsigned short)(hs.y & 0xFFFF));
        p3 = w * bf2f((unsigned short)(hs.y >> 16));
        p4 = w * bf2f((unsigned short)(hs.z & 0xFFFF));
        p5 = w * bf2f((unsigned short)(hs.z >> 16));
        p6 = w * bf2f((unsigned short)(hs.w & 0xFFFF));
        p7 = w * bf2f((unsigned short)(hs.w >> 16));
    }
    int cc = c < 64 ? c : 64;
    for (int i = 0; i < cc; i += 16) {  // 8 pairs = 16 neighbors per iter
        int i0 = i + half,      i1 = i + 2 + half;
        int i2 = i + 4 + half,  i3 = i + 6 + half;
        int i4 = i + 8 + half,  i5 = i + 10 + half;
        int i6 = i + 12 + half, i7 = i + 14 + half;
        int t0 = __shfl(tl, i0), t1 = __shfl(tl, i1);
        int t2 = __shfl(tl, i2), t3 = __shfl(tl, i3);
        int t4 = __shfl(tl, i4), t5 = __shfl(tl, i5);
        int t6 = __shfl(tl, i6), t7 = __shfl(tl, i7);
        float d0 = __shfl(dl, i0), d1 = __shfl(dl, i1);
        float d2 = __shfl(dl, i2), d3 = __shfl(dl, i3);
        float d4 = __shfl(dl, i4), d5 = __shfl(dl, i5);
        float d6 = __shfl(dl, i6), d7 = __shfl(dl, i7);
        uint4 h0 = H16[t0 * 32 + hl];
        uint4 h1 = H16[t1 * 32 + hl];
        uint4 h2 = H16[t2 * 32 + hl];
        uint4 h3 = H16[t3 * 32 + hl];
        uint4 h4 = H16[t4 * 32 + hl];
        uint4 h5 = H16[t5 * 32 + hl];
        uint4 h6 = H16[t6 * 32 + hl];
        uint4 h7 = H16[t7 * 32 + hl];
        ACC8(h0, d0) ACC8(h1, d1) ACC8(h2, d2) ACC8(h3, d3)
        ACC8(h4, d4) ACC8(h5, d5) ACC8(h6, d6) ACC8(h7, d7)
    }
    for (int i = 64; i < c; ++i) {  // rare: deduped degree > 64
        int t = a[i];
        float d = half ? 0.0f : dinv[t];
        uint4 h = H16[t * 32 + hl];
        ACC8(h, d)
    }
    p0 += __shfl(p0, lane ^ 32); p1 += __shfl(p1, lane ^ 32);
    p2 += __shfl(p2, lane ^ 32); p3 += __shfl(p3, lane ^ 32);
    p4 += __shfl(p4, lane ^ 32); p5 += __shfl(p5, lane ^ 32);
    p6 += __shfl(p6, lane ^ 32); p7 += __shfl(p7, lane ^ 32);
    p0 = fmaxf(p0 * ds, 0.0f); p1 = fmaxf(p1 * ds, 0.0f);
    p2 = fmaxf(p2 * ds, 0.0f); p3 = fmaxf(p3 * ds, 0.0f);
    p4 = fmaxf(p4 * ds, 0.0f); p5 = fmaxf(p5 * ds, 0.0f);
    p6 = fmaxf(p6 * ds, 0.0f); p7 = fmaxf(p7 * ds, 0.0f);
    float4 o;
    if (half) { o.x = p4; o.y = p5; o.z = p6; o.w = p7; }
    else      { o.x = p0; o.y = p1; o.z = p2; o.w = p3; }
    ((float4*)out)[s * 64 + hl * 2 + half] = o;
}

extern "C" void kernel_launch(void* const* d_in, const int* in_sizes, int n_in,
                              void* d_out, int out_size, void* d_ws, size_t ws_size,
                              hipStream_t stream) {
    const float* X = (const float*)d_in[0];
    const float* W = (const float*)d_in[1];
    const int* edges = (const int*)d_in[2];

    char* ws = (char*)d_ws;
    float* dinv        = (float*)(ws + OFF_DINV);
    int* cnt           = (int*)(ws + OFF_CNT);
    int* adj           = (int*)(ws + OFF_ADJ);
    unsigned short* Wt = (unsigned short*)(ws + OFF_WT);
    unsigned short* H  = (unsigned short*)(ws + OFF_H);
    int* region        = (int*)(ws + OFF_REG);
    unsigned* part32   = (unsigned*)(ws + OFF_PART);

    k_pre_bucket<<<PRE_BLKS + BKT_BLKS, 512, 0, stream>>>(W, Wt, edges, region);
    k_fillscan_gemm<<<NG + GEMM_BLKS, 512, 0, stream>>>(region, adj, cnt, part32, X, Wt, H);
    k_deg<<<(N / 4 + 255) / 256, 256, 0, stream>>>(part32, dinv);
    k_gather<<<N / 4, 256, 0, stream>>>(adj, cnt, dinv, H, (float*)d_out);
}